// Round 1
// baseline (6494.165 us; speedup 1.0000x reference)
//
#include <hip/hip_runtime.h>

typedef _Float16 half8 __attribute__((ext_vector_type(8)));
typedef float f32x4 __attribute__((ext_vector_type(4)));

#define MFMA16(a,b,c) __builtin_amdgcn_mfma_f32_16x16x32_f16((a),(b),(c),0,0,0)

constexpr int B_SZ = 128, S_LEN = 512, I_SZ = 512, H_SZ = 1024, O_SZ = 512;

// workspace layout (bytes)
constexpr size_t XW_OFF   = 0;                                            // f16 [S][B][H]
constexpr size_t X16_OFF  = XW_OFF   + (size_t)S_LEN * B_SZ * H_SZ * 2;   // f16 [B*S][I]
constexpr size_t WXHT_OFF = X16_OFF  + (size_t)B_SZ * S_LEN * I_SZ * 2;   // f16 [H][I]
constexpr size_t WHHT_OFF = WXHT_OFF + (size_t)H_SZ * I_SZ * 2;           // f16 [H][H]
constexpr size_t WYHT_OFF = WHHT_OFF + (size_t)H_SZ * H_SZ * 2;           // f16 [O][H]
constexpr size_t HBUF_OFF = WYHT_OFF + (size_t)O_SZ * H_SZ * 2;           // f16 [2][B][H]
constexpr size_t CNT_OFF  = HBUF_OFF + (size_t)2 * B_SZ * H_SZ * 2;       // u32 [8*64]

// ---------------- prep kernels ----------------

__global__ void k_cvt_x(const float* __restrict__ in, _Float16* __restrict__ out) {
  size_t i = ((size_t)blockIdx.x * 256 + threadIdx.x) * 8;
  float4 a = *(const float4*)(in + i);
  float4 b = *(const float4*)(in + i + 4);
  half8 h;
  h[0] = (_Float16)a.x; h[1] = (_Float16)a.y; h[2] = (_Float16)a.z; h[3] = (_Float16)a.w;
  h[4] = (_Float16)b.x; h[5] = (_Float16)b.y; h[6] = (_Float16)b.z; h[7] = (_Float16)b.w;
  *(half8*)(out + i) = h;
}

// out[n][k] = (f16) in[k][n]   (in: [K][N] f32, out: [N][K] f16)
__global__ void k_transpose_cvt(const float* __restrict__ in, _Float16* __restrict__ out,
                                int K, int N) {
  int k = blockIdx.x * 256 + threadIdx.x;
  int n = blockIdx.y;
  out[(size_t)n * K + k] = (_Float16)in[(size_t)k * N + n];
}

// ---------------- phase 1: xW = x @ W_xh + b -> f16 [S][B][H] ----------------

__launch_bounds__(256, 1)
__global__ void k_xw_gemm(const _Float16* __restrict__ A,   // [M=65536][512]
                          const _Float16* __restrict__ BT,  // [1024][512]
                          const float* __restrict__ bias,   // [1024]
                          _Float16* __restrict__ xw)        // [S][B][H]
{
  const int m0 = blockIdx.y * 128;
  const int n0 = blockIdx.x * 128;
  __shared__ __align__(16) _Float16 la[128][72];   // pad to 72 (144B rows, 16B aligned)
  __shared__ __align__(16) _Float16 lb[128][72];
  const int tid = threadIdx.x;
  const int w = tid >> 6, l = tid & 63;
  const int wr = w >> 1, wc = w & 1;
  const int cl = l & 15;
  const int kh = (l >> 4) << 3;
  const int rl = (l >> 4) << 2;

  f32x4 acc[4][4] = {};

  for (int kb = 0; kb < 512; kb += 64) {
    {
      const int r = tid >> 1, sg = tid & 1;
      const _Float16* ga = A  + (size_t)(m0 + r) * 512 + kb + sg * 32;
      const _Float16* gb = BT + (size_t)(n0 + r) * 512 + kb + sg * 32;
      _Float16* da = &la[r][sg * 32];
      _Float16* db = &lb[r][sg * 32];
      #pragma unroll
      for (int i = 0; i < 4; i++) *(half8*)(da + i * 8) = *(const half8*)(ga + i * 8);
      #pragma unroll
      for (int i = 0; i < 4; i++) *(half8*)(db + i * 8) = *(const half8*)(gb + i * 8);
    }
    __syncthreads();
    #pragma unroll
    for (int kk = 0; kk < 64; kk += 32) {
      half8 af[4], bf[4];
      #pragma unroll
      for (int mi = 0; mi < 4; mi++) af[mi] = *(const half8*)(&la[wr * 64 + mi * 16 + cl][kk + kh]);
      #pragma unroll
      for (int ni = 0; ni < 4; ni++) bf[ni] = *(const half8*)(&lb[wc * 64 + ni * 16 + cl][kk + kh]);
      #pragma unroll
      for (int mi = 0; mi < 4; mi++)
        #pragma unroll
        for (int ni = 0; ni < 4; ni++)
          acc[mi][ni] = MFMA16(af[mi], bf[ni], acc[mi][ni]);
    }
    __syncthreads();
  }

  #pragma unroll
  for (int mi = 0; mi < 4; mi++)
    #pragma unroll
    for (int ni = 0; ni < 4; ni++) {
      const int col = n0 + wc * 64 + ni * 16 + cl;
      const float bv = bias[col];
      #pragma unroll
      for (int r = 0; r < 4; r++) {
        const int m = m0 + wr * 64 + mi * 16 + rl + r;
        const int b = m >> 9;        // M rows are (b, s), S = 512
        const int s = m & 511;
        xw[((size_t)(s * B_SZ + b) << 10) + col] = (_Float16)(acc[mi][ni][r] + bv);
      }
    }
}

// ---------------- phase 2+3: persistent recurrence ----------------
// 8 groups x 16 batch rows; 32 wgs/group, each owns 32 H-columns (W_hh^T slice in LDS).
// Group g = bid & 7 so a group's wgs land on one XCD (perf heuristic only).

__launch_bounds__(128, 1)
__global__ void k_rnn(const _Float16* __restrict__ xw,
                      const _Float16* __restrict__ WhhT,   // [H][H]
                      const _Float16* __restrict__ WyhT,   // [O][H]
                      const float* __restrict__ Wby,
                      _Float16* __restrict__ hbuf,         // [2][B][H]
                      unsigned* __restrict__ cnt,          // [8*64]
                      float* __restrict__ out)             // [B][O]
{
  const int bid = blockIdx.x;
  const int g = bid & 7;
  const int j = bid >> 3;
  const int tid = threadIdx.x;
  const int w = tid >> 6;
  const int l = tid & 63;
  const int r0 = g << 4;            // batch-row base
  const int n0 = j << 5;            // H-column base
  const int cl = l & 15;
  const int kh = (l >> 4) << 3;
  const int rl = (l >> 4) << 2;
  const int colg = n0 + (w << 4) + cl;

  __shared__ __align__(16) _Float16 lw[32][1032];  // W_hh^T slice (pad 8 -> 2064B rows)
  __shared__ __align__(16) _Float16 lh[16][1032];  // h tile

  { // load W slice once
    const int r = tid >> 2, sg = tid & 3;
    const _Float16* src = WhhT + ((size_t)(n0 + r) << 10) + (sg << 8);
    _Float16* dst = &lw[r][sg << 8];
    #pragma unroll
    for (int i = 0; i < 32; i++)
      *(half8*)(dst + (i << 3)) = *(const half8*)(src + (i << 3));
  }

  const int hr = tid >> 3;          // staging: 16 rows, 8 threads/row
  const int hs = tid & 7;

  float xv[4];
  {
    const _Float16* p = xw + ((size_t)r0 << 10) + colg;   // t = 0 slab
    #pragma unroll
    for (int r = 0; r < 4; r++) xv[r] = (float)p[(size_t)(rl + r) << 10];
  }

  unsigned tgt = 0;
  for (int t = 0; t < 512; t++) {
    f32x4 acc0 = {}, acc1 = {};
    float xn[4] = {0.f, 0.f, 0.f, 0.f};
    if (t > 0) {
      { // stage h_t -> LDS (64B-interleaved to spread banks)
        const _Float16* hsrc = hbuf + (((size_t)(t & 1) << 7) + r0 + hr) * 1024 + (hs << 3);
        _Float16* ldst = &lh[hr][hs << 3];
        #pragma unroll
        for (int i = 0; i < 16; i++)
          *(half8*)(ldst + (i << 6)) = *(const half8*)(hsrc + (i << 6));
      }
      if (t < 511) { // prefetch next step's xW addend (overlaps MFMA)
        const _Float16* p = xw + (((size_t)(t + 1) << 7) + r0) * 1024 + colg;
        #pragma unroll
        for (int r = 0; r < 4; r++) xn[r] = (float)p[(size_t)(rl + r) << 10];
      }
      __syncthreads();
      #pragma unroll 4
      for (int kc = 0; kc < 32; kc += 2) {   // two interleaved acc chains for ILP
        half8 a0 = *(const half8*)(&lh[cl][(kc << 5) + kh]);
        half8 b0 = *(const half8*)(&lw[(w << 4) + cl][(kc << 5) + kh]);
        acc0 = MFMA16(a0, b0, acc0);
        half8 a1 = *(const half8*)(&lh[cl][((kc + 1) << 5) + kh]);
        half8 b1 = *(const half8*)(&lw[(w << 4) + cl][((kc + 1) << 5) + kh]);
        acc1 = MFMA16(a1, b1, acc1);
      }
    } else {
      const _Float16* p = xw + (((size_t)1 << 7) + r0) * 1024 + colg;
      #pragma unroll
      for (int r = 0; r < 4; r++) xn[r] = (float)p[(size_t)(rl + r) << 10];
    }

    { // h_{t+1} = tanh(xw_t + h_t @ W_hh)
      _Float16* hdst = hbuf + (((size_t)((t + 1) & 1) << 7) + r0) * 1024 + colg;
      #pragma unroll
      for (int r = 0; r < 4; r++) {
        float z = xv[r] + acc0[r] + acc1[r];
        hdst[(size_t)(rl + r) << 10] = (_Float16)tanhf(z);
      }
    }

    // group barrier (monotonic counter, no reset -> no ABA)
    __syncthreads();
    tgt += 32;
    if (tid == 0) {
      __threadfence();
      atomicAdd(&cnt[g << 6], 1u);
      while (__hip_atomic_load(&cnt[g << 6], __ATOMIC_RELAXED, __HIP_MEMORY_SCOPE_AGENT) < tgt)
        __builtin_amdgcn_s_sleep(1);
      __threadfence();
    }
    __syncthreads();
    #pragma unroll
    for (int r = 0; r < 4; r++) xv[r] = xn[r];
  }

  // ---------- phase 3: out = h_512 @ W_yh + b_y (h_512 is in hbuf[0]) ----------
  {
    const _Float16* hsrc = hbuf + ((size_t)(r0 + hr) << 10) + (hs << 3);
    _Float16* ldst = &lh[hr][hs << 3];
    #pragma unroll
    for (int i = 0; i < 16; i++)
      *(half8*)(ldst + (i << 6)) = *(const half8*)(hsrc + (i << 6));
    __syncthreads();
    if (w == 0) {
      f32x4 a0 = {}, a1 = {};
      const int oc = (j << 4) + cl;                  // 32 wgs x 16 cols = 512
      const _Float16* bsrc = WyhT + ((size_t)oc << 10);
      #pragma unroll 4
      for (int kc = 0; kc < 32; kc += 2) {
        half8 av = *(const half8*)(&lh[cl][(kc << 5) + kh]);
        half8 bv = *(const half8*)(bsrc + (kc << 5) + kh);
        a0 = MFMA16(av, bv, a0);
        half8 av1 = *(const half8*)(&lh[cl][((kc + 1) << 5) + kh]);
        half8 bv1 = *(const half8*)(bsrc + ((kc + 1) << 5) + kh);
        a1 = MFMA16(av1, bv1, a1);
      }
      const float bb = Wby[oc];
      #pragma unroll
      for (int r = 0; r < 4; r++)
        out[((size_t)(r0 + rl + r) << 9) + oc] = a0[r] + a1[r] + bb;
    }
  }
}

// ---------------- host ----------------

extern "C" void kernel_launch(void* const* d_in, const int* in_sizes, int n_in,
                              void* d_out, int out_size, void* d_ws, size_t ws_size,
                              hipStream_t stream) {
  const float* x   = (const float*)d_in[0];
  const float* Wxh = (const float*)d_in[1];
  const float* Whh = (const float*)d_in[2];
  const float* Wyh = (const float*)d_in[3];
  const float* Wbh = (const float*)d_in[4];
  const float* Wby = (const float*)d_in[5];
  float* out = (float*)d_out;

  char* ws = (char*)d_ws;
  _Float16* xw   = (_Float16*)(ws + XW_OFF);
  _Float16* x16  = (_Float16*)(ws + X16_OFF);
  _Float16* WxhT = (_Float16*)(ws + WXHT_OFF);
  _Float16* WhhT = (_Float16*)(ws + WHHT_OFF);
  _Float16* WyhT = (_Float16*)(ws + WYHT_OFF);
  _Float16* hbuf = (_Float16*)(ws + HBUF_OFF);
  unsigned* cnt  = (unsigned*)(ws + CNT_OFF);

  hipMemsetAsync(cnt, 0, 8 * 64 * sizeof(unsigned), stream);

  // prep
  k_cvt_x<<<16384, 256, 0, stream>>>(x, x16);                          // 128*512*512 / 8 / 256
  k_transpose_cvt<<<dim3(2, 1024), 256, 0, stream>>>(Wxh, WxhT, 512, 1024);
  k_transpose_cvt<<<dim3(4, 1024), 256, 0, stream>>>(Whh, WhhT, 1024, 1024);
  k_transpose_cvt<<<dim3(4, 512),  256, 0, stream>>>(Wyh, WyhT, 1024, 512);

  // phase 1: xW
  k_xw_gemm<<<dim3(8, 512), 256, 0, stream>>>(x16, WxhT, Wbh, xw);

  // phase 2+3: persistent recurrence + output projection
  k_rnn<<<256, 128, 0, stream>>>(xw, WhhT, WyhT, Wby, hbuf, cnt, out);
}

// Round 2
// 1883.011 us; speedup vs baseline: 3.4488x; 3.4488x over previous
//
#include <hip/hip_runtime.h>

typedef _Float16 half8 __attribute__((ext_vector_type(8)));
typedef float f32x4 __attribute__((ext_vector_type(4)));

#define MFMA16(a,b,c) __builtin_amdgcn_mfma_f32_16x16x32_f16((a),(b),(c),0,0,0)

constexpr int B_SZ = 128, S_LEN = 512, I_SZ = 512, H_SZ = 1024, O_SZ = 512;

// workspace layout (bytes)
constexpr size_t XW_OFF   = 0;                                            // f16 [S][B][H]
constexpr size_t X16_OFF  = XW_OFF   + (size_t)S_LEN * B_SZ * H_SZ * 2;   // f16 [B*S][I]
constexpr size_t WXHT_OFF = X16_OFF  + (size_t)B_SZ * S_LEN * I_SZ * 2;   // f16 [H][I]
constexpr size_t WHHT_OFF = WXHT_OFF + (size_t)H_SZ * I_SZ * 2;           // f16 [H][H]
constexpr size_t WYHT_OFF = WHHT_OFF + (size_t)H_SZ * H_SZ * 2;           // f16 [O][H]
constexpr size_t HBUF_OFF = WYHT_OFF + (size_t)O_SZ * H_SZ * 2;           // f16 [2][B][H] (u64-accessed)
constexpr size_t CNT_OFF  = HBUF_OFF + (size_t)2 * B_SZ * H_SZ * 2;       // u32 [8*64]

typedef unsigned long long u64;

__device__ __forceinline__ u64 ag_load(const u64* p) {
  return __hip_atomic_load(p, __ATOMIC_RELAXED, __HIP_MEMORY_SCOPE_AGENT);
}
__device__ __forceinline__ void ag_store(u64* p, u64 v) {
  __hip_atomic_store(p, v, __ATOMIC_RELAXED, __HIP_MEMORY_SCOPE_AGENT);
}

// ---------------- prep kernels ----------------

__global__ void k_cvt_x(const float* __restrict__ in, _Float16* __restrict__ out) {
  size_t i = ((size_t)blockIdx.x * 256 + threadIdx.x) * 8;
  float4 a = *(const float4*)(in + i);
  float4 b = *(const float4*)(in + i + 4);
  half8 h;
  h[0] = (_Float16)a.x; h[1] = (_Float16)a.y; h[2] = (_Float16)a.z; h[3] = (_Float16)a.w;
  h[4] = (_Float16)b.x; h[5] = (_Float16)b.y; h[6] = (_Float16)b.z; h[7] = (_Float16)b.w;
  *(half8*)(out + i) = h;
}

// out[n][k] = (f16) in[k][n]   (in: [K][N] f32, out: [N][K] f16)
__global__ void k_transpose_cvt(const float* __restrict__ in, _Float16* __restrict__ out,
                                int K, int N) {
  int k = blockIdx.x * 256 + threadIdx.x;
  int n = blockIdx.y;
  out[(size_t)n * K + k] = (_Float16)in[(size_t)k * N + n];
}

// ---------------- phase 1: xW = x @ W_xh + b -> f16 [S][B][H] ----------------

__launch_bounds__(256, 1)
__global__ void k_xw_gemm(const _Float16* __restrict__ A,   // [M=65536][512]
                          const _Float16* __restrict__ BT,  // [1024][512]
                          const float* __restrict__ bias,   // [1024]
                          _Float16* __restrict__ xw)        // [S][B][H]
{
  const int m0 = blockIdx.y * 128;
  const int n0 = blockIdx.x * 128;
  __shared__ __align__(16) _Float16 la[128][72];
  __shared__ __align__(16) _Float16 lb[128][72];
  const int tid = threadIdx.x;
  const int w = tid >> 6, l = tid & 63;
  const int wr = w >> 1, wc = w & 1;
  const int cl = l & 15;
  const int kh = (l >> 4) << 3;
  const int rl = (l >> 4) << 2;

  f32x4 acc[4][4] = {};

  for (int kb = 0; kb < 512; kb += 64) {
    {
      const int r = tid >> 1, sg = tid & 1;
      const _Float16* ga = A  + (size_t)(m0 + r) * 512 + kb + sg * 32;
      const _Float16* gb = BT + (size_t)(n0 + r) * 512 + kb + sg * 32;
      _Float16* da = &la[r][sg * 32];
      _Float16* db = &lb[r][sg * 32];
      #pragma unroll
      for (int i = 0; i < 4; i++) *(half8*)(da + i * 8) = *(const half8*)(ga + i * 8);
      #pragma unroll
      for (int i = 0; i < 4; i++) *(half8*)(db + i * 8) = *(const half8*)(gb + i * 8);
    }
    __syncthreads();
    #pragma unroll
    for (int kk = 0; kk < 64; kk += 32) {
      half8 af[4], bf[4];
      #pragma unroll
      for (int mi = 0; mi < 4; mi++) af[mi] = *(const half8*)(&la[wr * 64 + mi * 16 + cl][kk + kh]);
      #pragma unroll
      for (int ni = 0; ni < 4; ni++) bf[ni] = *(const half8*)(&lb[wc * 64 + ni * 16 + cl][kk + kh]);
      #pragma unroll
      for (int mi = 0; mi < 4; mi++)
        #pragma unroll
        for (int ni = 0; ni < 4; ni++)
          acc[mi][ni] = MFMA16(af[mi], bf[ni], acc[mi][ni]);
    }
    __syncthreads();
  }

  #pragma unroll
  for (int mi = 0; mi < 4; mi++)
    #pragma unroll
    for (int ni = 0; ni < 4; ni++) {
      const int col = n0 + wc * 64 + ni * 16 + cl;
      const float bv = bias[col];
      #pragma unroll
      for (int r = 0; r < 4; r++) {
        const int m = m0 + wr * 64 + mi * 16 + rl + r;
        const int b = m >> 9;        // M rows are (b, s), S = 512
        const int s = m & 511;
        xw[((size_t)(s * B_SZ + b) << 10) + col] = (_Float16)(acc[mi][ni][r] + bv);
      }
    }
}

// ---------------- phase 2+3: persistent recurrence ----------------
// 8 groups x 16 batch rows; 32 wgs/group, each owns 32 H-columns (W_hh^T slice in LDS).
// h exchange + barrier flag entirely via relaxed agent-scope (sc1/L3-point) atomics:
// no __threadfence -> no buffer_wbl2 L2-walks in the loop.

__launch_bounds__(128, 1)
__global__ void k_rnn(const _Float16* __restrict__ xw,
                      const _Float16* __restrict__ WhhT,   // [H][H]
                      const _Float16* __restrict__ WyhT,   // [O][H]
                      const float* __restrict__ Wby,
                      u64* __restrict__ hb64,              // [2][B][H/4] as u64
                      unsigned* __restrict__ cnt,          // [8*64]
                      float* __restrict__ out)             // [B][O]
{
  const int bid = blockIdx.x;
  const int g = bid & 7;
  const int j = bid >> 3;
  const int tid = threadIdx.x;
  const int w = tid >> 6;
  const int l = tid & 63;
  const int r0 = g << 4;            // batch-row base
  const int n0 = j << 5;            // H-column base
  const int cl = l & 15;
  const int kh = (l >> 4) << 3;
  const int rl = (l >> 4) << 2;
  const int colg = n0 + (w << 4) + cl;

  __shared__ __align__(16) _Float16 lw[32][1032];  // W_hh^T slice (pad 8 -> 2064B rows)
  __shared__ __align__(16) _Float16 lh[16][1032];  // h tile
  __shared__ __align__(16) _Float16 st[16][40];    // h-slice repack bounce (80B rows, 8B-aligned)

  { // load W slice once
    const int r = tid >> 2, sg = tid & 3;
    const _Float16* src = WhhT + ((size_t)(n0 + r) << 10) + (sg << 8);
    _Float16* dst = &lw[r][sg << 8];
    #pragma unroll
    for (int i = 0; i < 32; i++)
      *(half8*)(dst + (i << 3)) = *(const half8*)(src + (i << 3));
  }

  const int hr = tid >> 3;          // staging: 16 rows, 8 threads/row
  const int hs = tid & 7;

  float xv[4];
  {
    const _Float16* p = xw + ((size_t)r0 << 10) + colg;   // t = 0 slab
    #pragma unroll
    for (int r = 0; r < 4; r++) xv[r] = (float)p[(size_t)(rl + r) << 10];
  }

  unsigned tgt = 0;
  for (int t = 0; t < 512; t++) {
    f32x4 acc0 = {}, acc1 = {};
    float xn[4] = {0.f, 0.f, 0.f, 0.f};
    if (t > 0) {
      { // stage h_t -> LDS via L3-point u64 atomic loads (all issued before use)
        u64 v[32];
        const u64* hb = hb64 + (((size_t)(t & 1) << 7) + r0 + hr) * 256 + (hs << 1);
        #pragma unroll
        for (int i = 0; i < 16; i++) {
          v[2 * i]     = ag_load(hb + (i << 4));
          v[2 * i + 1] = ag_load(hb + (i << 4) + 1);
        }
        #pragma unroll
        for (int i = 0; i < 16; i++) {
          *(u64*)(&lh[hr][(hs << 3) + (i << 6)])     = v[2 * i];
          *(u64*)(&lh[hr][(hs << 3) + (i << 6) + 4]) = v[2 * i + 1];
        }
      }
      if (t < 511) { // prefetch next step's xW addend (overlaps MFMA)
        const _Float16* p = xw + (((size_t)(t + 1) << 7) + r0) * 1024 + colg;
        #pragma unroll
        for (int r = 0; r < 4; r++) xn[r] = (float)p[(size_t)(rl + r) << 10];
      }
      __syncthreads();
      #pragma unroll 4
      for (int kc = 0; kc < 32; kc += 2) {   // two interleaved acc chains for ILP
        half8 a0 = *(const half8*)(&lh[cl][(kc << 5) + kh]);
        half8 b0 = *(const half8*)(&lw[(w << 4) + cl][(kc << 5) + kh]);
        acc0 = MFMA16(a0, b0, acc0);
        half8 a1 = *(const half8*)(&lh[cl][((kc + 1) << 5) + kh]);
        half8 b1 = *(const half8*)(&lw[(w << 4) + cl][((kc + 1) << 5) + kh]);
        acc1 = MFMA16(a1, b1, acc1);
      }
    } else {
      const _Float16* p = xw + (((size_t)1 << 7) + r0) * 1024 + colg;
      #pragma unroll
      for (int r = 0; r < 4; r++) xn[r] = (float)p[(size_t)(rl + r) << 10];
    }

    // h_{t+1} = tanh(xw_t + h_t @ W_hh) -> repack via LDS bounce
    #pragma unroll
    for (int r = 0; r < 4; r++) {
      float z = xv[r] + acc0[r] + acc1[r];
      st[rl + r][(w << 4) + cl] = (_Float16)tanhf(z);
    }
    __syncthreads();
    { // u64 store to L3-visible hbuf (bypasses L2 dirty state)
      u64 pv = *(const u64*)&st[tid >> 3][(tid & 7) << 2];
      u64* dst = hb64 + (((size_t)((t + 1) & 1) << 7) + r0 + (tid >> 3)) * 256
               + (n0 >> 2) + (tid & 7);
      ag_store(dst, pv);
    }
    asm volatile("s_waitcnt vmcnt(0)" ::: "memory");   // my h is at the coherence point
    __syncthreads();                                    // whole wg's h is
    tgt += 32;
    if (tid == 0) {
      __hip_atomic_fetch_add(&cnt[g << 6], 1u, __ATOMIC_RELAXED, __HIP_MEMORY_SCOPE_AGENT);
      while (__hip_atomic_load(&cnt[g << 6], __ATOMIC_RELAXED, __HIP_MEMORY_SCOPE_AGENT) < tgt)
        __builtin_amdgcn_s_sleep(1);
    }
    __syncthreads();
    #pragma unroll
    for (int r = 0; r < 4; r++) xv[r] = xn[r];
  }

  // ---------- phase 3: out = h_512 @ W_yh + b_y (h_512 is in hbuf[0]) ----------
  {
    { // stage h_512 via the same L3-point loads
      u64 v[32];
      const u64* hb = hb64 + ((size_t)(r0 + hr)) * 256 + (hs << 1);
      #pragma unroll
      for (int i = 0; i < 16; i++) {
        v[2 * i]     = ag_load(hb + (i << 4));
        v[2 * i + 1] = ag_load(hb + (i << 4) + 1);
      }
      #pragma unroll
      for (int i = 0; i < 16; i++) {
        *(u64*)(&lh[hr][(hs << 3) + (i << 6)])     = v[2 * i];
        *(u64*)(&lh[hr][(hs << 3) + (i << 6) + 4]) = v[2 * i + 1];
      }
    }
    __syncthreads();
    if (w == 0) {
      f32x4 a0 = {}, a1 = {};
      const int oc = (j << 4) + cl;                  // 32 wgs x 16 cols = 512
      const _Float16* bsrc = WyhT + ((size_t)oc << 10);
      #pragma unroll 4
      for (int kc = 0; kc < 32; kc += 2) {
        half8 av = *(const half8*)(&lh[cl][(kc << 5) + kh]);
        half8 bv = *(const half8*)(bsrc + (kc << 5) + kh);
        a0 = MFMA16(av, bv, a0);
        half8 av1 = *(const half8*)(&lh[cl][((kc + 1) << 5) + kh]);
        half8 bv1 = *(const half8*)(bsrc + ((kc + 1) << 5) + kh);
        a1 = MFMA16(av1, bv1, a1);
      }
      const float bb = Wby[oc];
      #pragma unroll
      for (int r = 0; r < 4; r++)
        out[((size_t)(r0 + rl + r) << 9) + oc] = a0[r] + a1[r] + bb;
    }
  }
}

// ---------------- host ----------------

extern "C" void kernel_launch(void* const* d_in, const int* in_sizes, int n_in,
                              void* d_out, int out_size, void* d_ws, size_t ws_size,
                              hipStream_t stream) {
  const float* x   = (const float*)d_in[0];
  const float* Wxh = (const float*)d_in[1];
  const float* Whh = (const float*)d_in[2];
  const float* Wyh = (const float*)d_in[3];
  const float* Wbh = (const float*)d_in[4];
  const float* Wby = (const float*)d_in[5];
  float* out = (float*)d_out;

  char* ws = (char*)d_ws;
  _Float16* xw   = (_Float16*)(ws + XW_OFF);
  _Float16* x16  = (_Float16*)(ws + X16_OFF);
  _Float16* WxhT = (_Float16*)(ws + WXHT_OFF);
  _Float16* WhhT = (_Float16*)(ws + WHHT_OFF);
  _Float16* WyhT = (_Float16*)(ws + WYHT_OFF);
  u64*      hb64 = (u64*)(ws + HBUF_OFF);
  unsigned* cnt  = (unsigned*)(ws + CNT_OFF);

  hipMemsetAsync(cnt, 0, 8 * 64 * sizeof(unsigned), stream);

  // prep
  k_cvt_x<<<16384, 256, 0, stream>>>(x, x16);
  k_transpose_cvt<<<dim3(2, 1024), 256, 0, stream>>>(Wxh, WxhT, 512, 1024);
  k_transpose_cvt<<<dim3(4, 1024), 256, 0, stream>>>(Whh, WhhT, 1024, 1024);
  k_transpose_cvt<<<dim3(4, 512),  256, 0, stream>>>(Wyh, WyhT, 1024, 512);

  // phase 1: xW
  k_xw_gemm<<<dim3(8, 512), 256, 0, stream>>>(x16, WxhT, Wbh, xw);

  // phase 2+3: persistent recurrence + output projection
  k_rnn<<<256, 128, 0, stream>>>(xw, WhhT, WyhT, Wby, hb64, cnt, out);
}